// Round 2
// baseline (533.924 us; speedup 1.0000x reference)
//
#include <hip/hip_runtime.h>

// ONINorm: per-group (g=8, c=32) whitening via Newton-Schulz inverse sqrt.
// Input (262144, 256) fp32. reshape(8,-1,32): group g = contiguous 32MB slab,
// samples = consecutive 32-float chunks.
//
// R2 = R1 resubmit (R1 bench died to container infra, no counters).
// Only change: drop __launch_bounds__(256,4) on k1 -> no forced 128-VGPR cap,
// avoids spill risk on the 8x8 accumulator (64 acc regs + operands ~110 VGPR,
// still 4 waves/SIMD naturally).
//
// R1 theory (unchanged): k1/k3 LDS-pipe-bound, not HBM-bound.
//  k1: 8x8 per-lane Gram tiles (was 4x4) -> LDS bytes/sample halved; 4 sample
//      slots per wave reduced via shfl_xor(16/32); ZS1=36 keeps <=2-way banks.
//  k2: NS matmuls on 256 threads with float4 row-segments (was 1024 scalar).
//  k3: 4 samples/thread (tile=128), M fragment reused 4x -> LDS reads/sample
//      24 -> 16, under the HBM floor.

#define ROWS 262144
#define COLS 256
#define NG 8
#define NC 32
#define SPG 262144            // samples per group
#define K1_BLOCKS 1024
#define K1_BPG 128            // blocks per group
#define K1_SAMPLES 2048       // samples per block
#define K1_TILES 32
#define K3_BLOCKS 2048
#define K3_BPG 256
#define K3_SAMPLES 1024
#define K3_TILES 8            // 1024 / 128
#define TILE 64               // k1 samples per LDS tile
#define K3_TILE 128           // k3 samples per LDS tile
#define PSTRIDE 1056          // 1024 gram + 32 sums
#define ZS1 36                // k1 LDS sample stride (16B aligned, 2-way max)
#define ZS3 40                // k3 LDS sample stride (16B aligned, 2-way max)

__global__ __launch_bounds__(256) void k1_stats(const float* __restrict__ x,
                                                float* __restrict__ part) {
  __shared__ __align__(16) float zt[TILE * ZS1];     // 9.2 KB
  __shared__ __align__(16) float red[4 * PSTRIDE];   // 16.9 KB
  const int t = threadIdx.x;
  const int b = blockIdx.x;
  const int g = b >> 7, lb = b & 127;
  const int w = t >> 6;            // wave 0..3
  const int l = t & 63;
  const int q = l >> 4;            // sample slot 0..3 within wave
  const int p = l & 15;            // tile position 0..15
  const int li = p >> 2, lj = p & 3;  // 8x8 tile coords (x8 rows, x8 cols)

  float acc[8][8] = {{0.f}};
  float sm[8] = {0.f};

  const float* gb = x + ((size_t)g * SPG + (size_t)lb * K1_SAMPLES) * NC;
  const int si0 = t >> 3, q0 = t & 7;
  const int si1 = (t + 256) >> 3;   // (t+256)&7 == t&7 since 256%8==0

  for (int tile = 0; tile < K1_TILES; ++tile) {
    const float* tb = gb + (size_t)tile * (TILE * NC);
    float4 v0 = *(const float4*)(tb + t * 4);
    float4 v1 = *(const float4*)(tb + (t + 256) * 4);
    __syncthreads();  // previous tile's compute done reading zt
    *(float4*)&zt[si0 * ZS1 + q0 * 4] = v0;
    *(float4*)&zt[si1 * ZS1 + q0 * 4] = v1;
    __syncthreads();
#pragma unroll
    for (int it = 0; it < 4; ++it) {
      const float* zp = &zt[(w * 16 + it * 4 + q) * ZS1];
      float4 r0 = *(const float4*)(zp + li * 8);
      float4 r1 = *(const float4*)(zp + li * 8 + 4);
      float4 c0 = *(const float4*)(zp + lj * 8);
      float4 c1 = *(const float4*)(zp + lj * 8 + 4);
      float rr[8] = {r0.x, r0.y, r0.z, r0.w, r1.x, r1.y, r1.z, r1.w};
      float cc[8] = {c0.x, c0.y, c0.z, c0.w, c1.x, c1.y, c1.z, c1.w};
#pragma unroll
      for (int i = 0; i < 8; ++i) {
        sm[i] += rr[i];
#pragma unroll
        for (int j = 0; j < 8; ++j) acc[i][j] += rr[i] * cc[j];
      }
    }
  }

  // reduce the 4 sample slots (lane bits 4,5) in-register
#pragma unroll
  for (int i = 0; i < 8; ++i) {
#pragma unroll
    for (int j = 0; j < 8; ++j) {
      acc[i][j] += __shfl_xor(acc[i][j], 16);
      acc[i][j] += __shfl_xor(acc[i][j], 32);
    }
    sm[i] += __shfl_xor(sm[i], 16);
    sm[i] += __shfl_xor(sm[i], 32);
  }

  if (q == 0) {  // lanes 0..15 hold the wave's full 8x8 tiles
    float* rw = &red[w * PSTRIDE];
#pragma unroll
    for (int i = 0; i < 8; ++i) {
      *(float4*)&rw[(li * 8 + i) * 32 + lj * 8] =
          make_float4(acc[i][0], acc[i][1], acc[i][2], acc[i][3]);
      *(float4*)&rw[(li * 8 + i) * 32 + lj * 8 + 4] =
          make_float4(acc[i][4], acc[i][5], acc[i][6], acc[i][7]);
    }
    if (lj == 0) {
      *(float4*)&rw[1024 + li * 8] = make_float4(sm[0], sm[1], sm[2], sm[3]);
      *(float4*)&rw[1024 + li * 8 + 4] = make_float4(sm[4], sm[5], sm[6], sm[7]);
    }
  }
  __syncthreads();
  float* po = part + (size_t)b * PSTRIDE;
  for (int e = t; e < PSTRIDE; e += 256)
    po[e] = red[e] + red[PSTRIDE + e] + red[2 * PSTRIDE + e] + red[3 * PSTRIDE + e];
}

__global__ __launch_bounds__(1024) void k2_solve(const float* __restrict__ part,
                                                 float* __restrict__ mt,
                                                 float* __restrict__ bias) {
  // 36-float row stride: float4-aligned, rotates banks by 4 per row
  __shared__ __align__(16) float S[NC * 36], Bm[NC * 36], T1[NC * 36], T2[NC * 36];
  __shared__ float mu[NC];
  __shared__ float red[1024];
  const int g = blockIdx.x;
  const int t = threadIdx.x;
  const int c = t >> 5, d = t & 31;
  const float* pb = part + (size_t)g * K1_BPG * PSTRIDE;

  float gs = 0.f;
  for (int b = 0; b < K1_BPG; ++b) gs += pb[(size_t)b * PSTRIDE + t];
  if (t < NC) {
    float cs = 0.f;
    for (int b = 0; b < K1_BPG; ++b) cs += pb[(size_t)b * PSTRIDE + 1024 + t];
    mu[t] = cs * (1.f / (float)SPG);
  }
  __syncthreads();

  float Sv = gs - (float)SPG * mu[c] * mu[d] + ((c == d) ? 1e-5f : 0.f);
  red[t] = Sv * Sv;
  __syncthreads();
  for (int off = 512; off > 0; off >>= 1) {
    if (t < off) red[t] += red[t + off];
    __syncthreads();
  }
  const float normS = sqrtf(red[0]);
  S[c * 36 + d] = Sv * (1.f / normS);
  Bm[c * 36 + d] = (c == d) ? 1.f : 0.f;
  __syncthreads();

  // Newton-Schulz: 256 threads, each owns row c2, float4 column block d4
  const int c2 = t >> 3, d4 = (t & 7) * 4;
  for (int it = 0; it < 5; ++it) {
    if (t < 256) {
      float4 a = make_float4(0.f, 0.f, 0.f, 0.f);
#pragma unroll
      for (int kk = 0; kk < NC; ++kk) {
        const float s = Bm[c2 * 36 + kk];
        const float4 b4 = *(const float4*)&Bm[kk * 36 + d4];
        a.x += s * b4.x; a.y += s * b4.y; a.z += s * b4.z; a.w += s * b4.w;
      }
      *(float4*)&T1[c2 * 36 + d4] = a;
    }
    __syncthreads();
    if (t < 256) {
      float4 a = make_float4(0.f, 0.f, 0.f, 0.f);
#pragma unroll
      for (int kk = 0; kk < NC; ++kk) {
        const float s = T1[c2 * 36 + kk];
        const float4 b4 = *(const float4*)&Bm[kk * 36 + d4];
        a.x += s * b4.x; a.y += s * b4.y; a.z += s * b4.z; a.w += s * b4.w;
      }
      *(float4*)&T2[c2 * 36 + d4] = a;
    }
    __syncthreads();
    if (t < 256) {
      float4 a = make_float4(0.f, 0.f, 0.f, 0.f);
#pragma unroll
      for (int kk = 0; kk < NC; ++kk) {
        const float s = T2[c2 * 36 + kk];
        const float4 b4 = *(const float4*)&S[kk * 36 + d4];
        a.x += s * b4.x; a.y += s * b4.y; a.z += s * b4.z; a.w += s * b4.w;
      }
      // each thread reads/writes only its own Bm float4 here -> no hazard
      float4 bm = *(const float4*)&Bm[c2 * 36 + d4];
      bm.x = 1.5f * bm.x - 0.5f * a.x;
      bm.y = 1.5f * bm.y - 0.5f * a.y;
      bm.z = 1.5f * bm.z - 0.5f * a.z;
      bm.w = 1.5f * bm.w - 0.5f * a.w;
      *(float4*)&Bm[c2 * 36 + d4] = bm;
    }
    __syncthreads();
  }

  const float Mv = Bm[c * 36 + d] * (1.f / sqrtf(normS));
  mt[g * 1024 + d * 32 + c] = Mv;  // transposed for k3's read pattern
  red[t] = Mv * mu[d];
  __syncthreads();
  for (int off = 16; off > 0; off >>= 1) {
    if (d < off) red[t] += red[t + off];
    __syncthreads();
  }
  if (d == 0) bias[g * 32 + c] = red[t];
}

__global__ __launch_bounds__(256) void k3_apply(const float* __restrict__ x,
                                                const float* __restrict__ mt,
                                                const float* __restrict__ bias,
                                                float* __restrict__ out) {
  __shared__ __align__(16) float Mt[1024];            // 4 KB
  __shared__ __align__(16) float zt[K3_TILE * ZS3];   // 20.5 KB
  const int t = threadIdx.x;
  const int b = blockIdx.x;
  const int g = b >> 8, lb = b & 255;
  const int k = t & 7, sl = t >> 3;   // sl 0..31

  *(float4*)&Mt[t * 4] = *(const float4*)&mt[g * 1024 + t * 4];
  float4 bi = *(const float4*)&bias[g * 32 + k * 4];
  const size_t base = ((size_t)g * SPG + (size_t)lb * K3_SAMPLES) * NC;

  for (int tile = 0; tile < K3_TILES; ++tile) {
    const float* tb = x + base + (size_t)tile * (K3_TILE * NC);
    float4 v0 = *(const float4*)(tb + t * 4);
    float4 v1 = *(const float4*)(tb + t * 4 + 1024);
    float4 v2 = *(const float4*)(tb + t * 4 + 2048);
    float4 v3 = *(const float4*)(tb + t * 4 + 3072);
    __syncthreads();  // prior compute done reading zt (covers Mt load on tile 0)
    *(float4*)&zt[sl * ZS3 + k * 4] = v0;
    *(float4*)&zt[(sl + 32) * ZS3 + k * 4] = v1;
    *(float4*)&zt[(sl + 64) * ZS3 + k * 4] = v2;
    *(float4*)&zt[(sl + 96) * ZS3 + k * 4] = v3;
    __syncthreads();

    float acc0[4] = {0, 0, 0, 0}, acc1[4] = {0, 0, 0, 0};
    float acc2[4] = {0, 0, 0, 0}, acc3[4] = {0, 0, 0, 0};
    const float* z0 = &zt[sl * ZS3];
    const float* z1 = &zt[(sl + 32) * ZS3];
    const float* z2 = &zt[(sl + 64) * ZS3];
    const float* z3 = &zt[(sl + 96) * ZS3];
#pragma unroll
    for (int dq = 0; dq < 8; ++dq) {
      float4 za4 = *(const float4*)(z0 + dq * 4);
      float4 zb4 = *(const float4*)(z1 + dq * 4);
      float4 zc4 = *(const float4*)(z2 + dq * 4);
      float4 zd4 = *(const float4*)(z3 + dq * 4);
      const float* za = (const float*)&za4;
      const float* zb = (const float*)&zb4;
      const float* zc = (const float*)&zc4;
      const float* zd = (const float*)&zd4;
#pragma unroll
      for (int dd = 0; dd < 4; ++dd) {
        float4 m4 = *(const float4*)&Mt[(dq * 4 + dd) * 32 + k * 4];
        acc0[0] += m4.x * za[dd]; acc0[1] += m4.y * za[dd];
        acc0[2] += m4.z * za[dd]; acc0[3] += m4.w * za[dd];
        acc1[0] += m4.x * zb[dd]; acc1[1] += m4.y * zb[dd];
        acc1[2] += m4.z * zb[dd]; acc1[3] += m4.w * zb[dd];
        acc2[0] += m4.x * zc[dd]; acc2[1] += m4.y * zc[dd];
        acc2[2] += m4.z * zc[dd]; acc2[3] += m4.w * zc[dd];
        acc3[0] += m4.x * zd[dd]; acc3[1] += m4.y * zd[dd];
        acc3[2] += m4.z * zd[dd]; acc3[3] += m4.w * zd[dd];
      }
    }
    float* ob = out + base + (size_t)tile * (K3_TILE * NC);
    *(float4*)(ob + sl * 32 + k * 4) =
        make_float4(acc0[0] - bi.x, acc0[1] - bi.y, acc0[2] - bi.z, acc0[3] - bi.w);
    *(float4*)(ob + (sl + 32) * 32 + k * 4) =
        make_float4(acc1[0] - bi.x, acc1[1] - bi.y, acc1[2] - bi.z, acc1[3] - bi.w);
    *(float4*)(ob + (sl + 64) * 32 + k * 4) =
        make_float4(acc2[0] - bi.x, acc2[1] - bi.y, acc2[2] - bi.z, acc2[3] - bi.w);
    *(float4*)(ob + (sl + 96) * 32 + k * 4) =
        make_float4(acc3[0] - bi.x, acc3[1] - bi.y, acc3[2] - bi.z, acc3[3] - bi.w);
  }
}

extern "C" void kernel_launch(void* const* d_in, const int* in_sizes, int n_in,
                              void* d_out, int out_size, void* d_ws, size_t ws_size,
                              hipStream_t stream) {
  (void)in_sizes; (void)n_in; (void)out_size; (void)ws_size;
  const float* x = (const float*)d_in[0];
  float* out = (float*)d_out;
  float* ws = (float*)d_ws;
  float* part = ws;                                        // 1024 * 1056 floats
  float* mt   = ws + (size_t)K1_BLOCKS * PSTRIDE;          // 8 * 1024 floats
  float* bias = mt + NG * 1024;                            // 8 * 32 floats

  k1_stats<<<K1_BLOCKS, 256, 0, stream>>>(x, part);
  k2_solve<<<NG, 1024, 0, stream>>>(part, mt, bias);
  k3_apply<<<K3_BLOCKS, 256, 0, stream>>>(x, mt, bias, out);
}